// Round 13
// baseline (91.277 us; speedup 1.0000x reference)
//
#include <hip/hip_runtime.h>

// LIF neuron scan: v = v*0.5 + x[t]; s = (v - 0.5 > 0); v -= s*0.5
// Round 12 -> 13: R12's correctness failure = race on the reused LDS tile
// (walk-A ds_reads vs pass-B ds_writes WAR; staging-write vs walk RAW) --
// relied on in-order DS + compiler alias analysis over opaque f/13 offsets.
// Fix: explicit __syncthreads() at each phase boundary. For 1-wave blocks a
// barrier = just the waitcnt drain, and each drain sits where a data wait
// must happen anyway: the post-walk-A barrier's vmcnt(0) IS the planned wait
// for the pass-B loads (issued before walk A, latency hidden under it).
// Structure otherwise identical to R12: pass A (48 steps) + pass B (52) share
// one 64x13-f4 tile (14.3KB total -> 11 blocks/CU vs R11's 6), stride-13
// bank-quads cycle all 8 residues -> 2 lanes/bank = conflict-free. Bit-pack
// + expansion store verbatim from R10/R11 (0 conflicts, exact WRITE_SIZE).

#define T_STEPS 100
#define T_VEC   25      // f4 per row in global
#define ROWS    64      // rows per block == blockDim.x (one wave)
#define CA      12      // pass-A f4 chunks (48 steps)
#define CB      13      // pass-B f4 chunks (52 steps)
#define LSTRIDE 13      // tile row stride in f4
#define DECAY   0.5f
#define VTH     0.5f

typedef float vfloat4 __attribute__((ext_vector_type(4)));

__global__ __launch_bounds__(64, 3) void lif_kernel(const float* __restrict__ x,
                                                    float* __restrict__ out,
                                                    int n_rows) {
    __shared__ vfloat4 tile[ROWS * LSTRIDE];   // 13,312 B
    __shared__ unsigned int bits[ROWS * 4];    //  1,024 B -> 14,336 total

    const int lane = threadIdx.x;
    const int row0 = blockIdx.x * ROWS;
    const int gf0 = row0 * T_VEC;                    // f4 index (fits int)
    const int total_f4 = n_rows * T_VEC;

    const vfloat4* __restrict__ xb = reinterpret_cast<const vfloat4*>(x);
    const vfloat4 vzero = {0.0f, 0.0f, 0.0f, 0.0f};

    // ---- Pass A stage: coalesced loads (64 rows x 12 f4) -> tile ----
    {
        vfloat4 st[CA];
        #pragma unroll
        for (int k = 0; k < CA; ++k) {
            int f = k * 64 + lane;                   // 0..767
            int r = f / CA, c = f % CA;
            int g = gf0 + r * T_VEC + c;
            st[k] = (g < total_f4) ? xb[g] : vzero;
        }
        #pragma unroll
        for (int k = 0; k < CA; ++k) {
            int f = k * 64 + lane;
            int r = f / CA, c = f % CA;
            tile[r * LSTRIDE + c] = st[k];
        }
    }
    // Fence #1 BEFORE issuing pass-B loads (so its vmcnt(0) only covers the
    // already-consumed pass-A loads). Orders stage-A writes vs walk-A reads.
    __syncthreads();

    // ---- Pass B loads issued NOW; latency hides under pass-A walk ----
    vfloat4 sb[CB];
    #pragma unroll
    for (int k = 0; k < CB; ++k) {
        int f = k * 64 + lane;                       // 0..831
        int r = f / CB, c = f % CB;
        int g = gf0 + r * T_VEC + CA + c;
        sb[k] = (g < total_f4) ? xb[g] : vzero;
    }
    __builtin_amdgcn_sched_barrier(0);               // pin: loads issue first

    // ---- Walk pass A: 48 serial steps from tile, pack bits ----
    unsigned int pk0 = 0, pk1 = 0, pk2 = 0, pk3 = 0;
    float v = 0.0f;
    #pragma unroll
    for (int c = 0; c < CA; ++c) {
        vfloat4 xs = tile[lane * LSTRIDE + c];
        #pragma unroll
        for (int k = 0; k < 4; ++k) {
            // v*0.5 exact (pow2); conditional -0.5 exact -> bitwise == ref.
            v = v * DECAY + xs[k];
            bool s = (v - VTH > 0.0f);
            v -= s ? VTH : 0.0f;
            unsigned int bit = s ? 1u : 0u;
            const int b = c * 4 + k;                 // 0..47, compile-time
            if (b < 32) pk0 |= bit << b;
            else        pk1 |= bit << (b - 32);
        }
    }
    // Fence #2: WAR fence (walk-A reads before stage-B overwrites) AND the
    // planned vmcnt(0) wait point for the pass-B loads.
    __syncthreads();

    // ---- Pass B stage: ds_write the prefetched data ----
    #pragma unroll
    for (int k = 0; k < CB; ++k) {
        int f = k * 64 + lane;
        int r = f / CB, c = f % CB;
        tile[r * LSTRIDE + c] = sb[k];
    }
    // Fence #3: RAW fence (stage-B writes before walk-B reads).
    __syncthreads();

    // ---- Walk pass B: 52 serial steps ----
    #pragma unroll
    for (int c = 0; c < CB; ++c) {
        vfloat4 xs = tile[lane * LSTRIDE + c];
        #pragma unroll
        for (int k = 0; k < 4; ++k) {
            v = v * DECAY + xs[k];
            bool s = (v - VTH > 0.0f);
            v -= s ? VTH : 0.0f;
            unsigned int bit = s ? 1u : 0u;
            const int b = 48 + c * 4 + k;            // 48..99, compile-time
            if (b < 64)      pk1 |= bit << (b - 32);
            else if (b < 96) pk2 |= bit << (b - 64);
            else             pk3 |= bit << (b - 96);
        }
    }

    // ---- Bits to LDS, fence, expand ----
    {
        uint4 w; w.x = pk0; w.y = pk1; w.z = pk2; w.w = pk3;
        reinterpret_cast<uint4*>(bits)[lane] = w;
    }
    __syncthreads();

    // ---- Expand + coalesced full-line stores (R10: 0 conflicts, exact) ----
    vfloat4* __restrict__ ob = reinterpret_cast<vfloat4*>(out);
    #pragma unroll
    for (int i = 0; i < T_VEC; ++i) {
        int f = i * 64 + lane;                       // 0..1599
        int g = gf0 + f;
        if (g < total_f4) {
            int r  = f / T_VEC;
            int c4 = f % T_VEC;
            unsigned int word = bits[r * 4 + (c4 >> 3)];
            int shift = (c4 & 7) * 4;
            unsigned int nib = (word >> shift) & 0xFu;
            vfloat4 s;
            s.x = (nib & 1u) ? 1.0f : 0.0f;
            s.y = (nib & 2u) ? 1.0f : 0.0f;
            s.z = (nib & 4u) ? 1.0f : 0.0f;
            s.w = (nib & 8u) ? 1.0f : 0.0f;
            ob[g] = s;
        }
    }
}

extern "C" void kernel_launch(void* const* d_in, const int* in_sizes, int n_in,
                              void* d_out, int out_size, void* d_ws, size_t ws_size,
                              hipStream_t stream) {
    const float* x = (const float*)d_in[0];
    float* out = (float*)d_out;

    int n_rows = in_sizes[0] / T_STEPS;         // 32 * 16384 = 524288
    int grid = (n_rows + ROWS - 1) / ROWS;      // 8192

    lif_kernel<<<grid, ROWS, 0, stream>>>(x, out, n_rows);
}